// Round 20
// baseline (100.364 us; speedup 1.0000x reference)
//
#include <hip/hip_runtime.h>

namespace {
constexpr int N_ = 8, C_ = 32, H_ = 256, W_ = 512, DISP_ = 25;
constexpr int CH = H_ * W_;   // elements between channels / disparities
constexpr int TILE = 256;     // output columns per block
constexpr int NSS = C_ / 2;   // 16 supersteps, 2 channels packed per step
constexpr int YST = 288;      // staged y cols: [tb-12, tb+276)
constexpr int BUF = 296;      // u32 stride per buffer (288 + 8 pad; 16B-aligned)
}

typedef __attribute__((ext_vector_type(2))) _Float16 h2;
typedef __attribute__((ext_vector_type(4))) float f4;  // native vector for nt-store

__device__ __forceinline__ h2 u2h(unsigned u) { return __builtin_bit_cast(h2, u); }
__device__ __forceinline__ unsigned pk(float a, float b) {
  return __builtin_bit_cast(unsigned, __builtin_amdgcn_cvt_pkrtz(a, b));
}

// r20 = r18 (packed-f16 pairs + fdot2 + nt-stores, 66.2 us) with ONE change:
// x never touches LDS. r19 post-mortem: LDS is the tightest pipe (~70-77%:
// 32 waves/CU x 4 ds_read_b128/superstep + 3.4M conflict cyc); HBM 56%,
// VALU 54%. Each thread's 4 cols need exactly x[w0..w0+3] x 2 ch -> two
// coalesced float4 global loads straight to regs, packed in-reg (4 cvt_pkrtz).
// 4 G-waves redundantly load the same x (L1-served, L1 at 33%). LDS reads
// 4->3 b128 (-25%), writes -40%. Schedule: pack xpk at loop top (frees xl),
// then issue XLOAD/YLOAD(s+1) with a full compute phase before the barrier's
// vmcnt drain. Regs ~60 <= 64 cap of (256,8); WRITE_SIZE spill tripwire.
template <int G>
__device__ __forceinline__ void body(const float* xb, const float* py0,
                                     const float* py1, bool extra,
                                     float* __restrict__ op, unsigned* lds,
                                     int tid, int w0l, int w0g) {
  constexpr int I0 = (G == 0) ? 0 : (G == 1) ? 7 : (G == 2) ? 13 : 19;
  constexpr int NI = (G == 0) ? 7 : 6;
  constexpr int OFF = (G == 0) ? 4 : (G == 1) ? 0 : (G == 2) ? -8 : -12;

  const h2 one = {(_Float16)1.0f, (_Float16)1.0f};

  float acc[NI][4];
#pragma unroll
  for (int il = 0; il < NI; ++il)
#pragma unroll
    for (int cw = 0; cw < 4; ++cw) acc[il][cw] = 0.0f;

  float4 xl0, xl1;          // x cols w0..w0+3, channels 2s / 2s+1
  float b0, b1, c0, c1;     // y staging

#define YLOAD()                                                           \
  do {                                                                    \
    b0 = py0[0]; b1 = py0[CH];                                            \
    if (extra) { c0 = py1[0]; c1 = py1[CH]; }                             \
    py0 += 2 * CH; py1 += 2 * CH;                                         \
  } while (0)

#define XLOAD(s)                                                          \
  do {                                                                    \
    const float* xc = xb + (size_t)(2 * (s)) * CH;                        \
    xl0 = *reinterpret_cast<const float4*>(xc);                           \
    xl1 = *reinterpret_cast<const float4*>(xc + CH);                      \
  } while (0)

#define YWRITE(bsel)                                                      \
  do {                                                                    \
    unsigned* wp = lds + (bsel)*BUF;                                      \
    wp[tid] = pk(b0, b1);                                                 \
    if (extra) wp[256 + tid] = pk(c0, c1);                                \
  } while (0)

#define COMPUTE(bsel)                                                     \
  do {                                                                    \
    const unsigned* bp = lds + (bsel)*BUF;                                \
    const unsigned* yp = bp + w0l + (OFF + 12);                           \
    const uint4 q0 = *reinterpret_cast<const uint4*>(yp);                 \
    const uint4 q1 = *reinterpret_cast<const uint4*>(yp + 4);             \
    const uint4 q2 = *reinterpret_cast<const uint4*>(yp + 8);             \
    const unsigned yw[12] = {q0.x, q0.y, q0.z, q0.w, q1.x, q1.y, q1.z,    \
                             q1.w, q2.x, q2.y, q2.z, q2.w};               \
    _Pragma("unroll") for (int il = 0; il < NI; ++il) {                   \
      _Pragma("unroll") for (int cw = 0; cw < 4; ++cw) {                  \
        h2 d = u2h(xpk[cw]) - u2h(yw[cw + 12 - (I0 + il) - OFF]);         \
        h2 a = u2h(__builtin_bit_cast(unsigned, d) & 0x7FFF7FFFu);        \
        acc[il][cw] = __builtin_amdgcn_fdot2(a, one, acc[il][cw], false); \
      }                                                                   \
    }                                                                     \
  } while (0)

  // Prologue: superstep 0 (x to regs, y to LDS buffer 0).
  XLOAD(0);
  YLOAD();
  YWRITE(0);
  __syncthreads();

  int cb = 0;
#pragma unroll 1
  for (int s = 0; s < NSS; ++s) {
    // Consume xl into packed form, freeing xl for the next prefetch.
    const unsigned xpk[4] = {pk(xl0.x, xl1.x), pk(xl0.y, xl1.y),
                             pk(xl0.z, xl1.z), pk(xl0.w, xl1.w)};
    const bool more = (s + 1 < NSS);
    if (more) { XLOAD(s + 1); YLOAD(); }  // full compute phase of slack
    COMPUTE(cb);                          // 3 ds_read_b128 + fdot2 chain
    if (more) YWRITE(cb ^ 1);             // waits on y loads only
    __syncthreads();                      // writes visible; buffers ordered
    cb ^= 1;
  }

#undef YLOAD
#undef XLOAD
#undef YWRITE
#undef COMPUTE

  // Epilogue: zero out-of-overlap (w,i) pairs; NON-TEMPORAL stores (output
  // is write-once/never-read -> evict-first keeps it out of L2/L3).
#pragma unroll
  for (int il = 0; il < NI; ++il) {
    const int i = I0 + il;
    const int j0 = w0g - i + 12;  // y column used by cw=0
    f4 v;
    v.x = ((unsigned)(j0 + 0) < (unsigned)W_) ? acc[il][0] : 0.0f;
    v.y = ((unsigned)(j0 + 1) < (unsigned)W_) ? acc[il][1] : 0.0f;
    v.z = ((unsigned)(j0 + 2) < (unsigned)W_) ? acc[il][2] : 0.0f;
    v.w = ((unsigned)(j0 + 3) < (unsigned)W_) ? acc[il][3] : 0.0f;
    __builtin_nontemporal_store(v, reinterpret_cast<f4*>(op + (size_t)i * CH));
  }
}

__global__ __launch_bounds__(256, 8) void rescost_kernel(
    const float* __restrict__ x, const float* __restrict__ y,
    float* __restrict__ out) {
  __shared__ __align__(16) unsigned lds[2 * BUF];  // 2368 B, y only

  const int tid = threadIdx.x;
  const int tl = tid & 63;   // column group within tile: w0l = 4*tl
  const int g = tid >> 6;    // disparity group (wave-uniform)
  const int bid = blockIdx.x;
  const int tile = bid & 1;  // which 256-col half of the row
  const int r = bid >> 1;    // row in [0, N*H)
  const int n = r >> 8;      // H = 256
  const int h = r & (H_ - 1);
  const int tb = tile * TILE;
  const int w0l = tl << 2;
  const int w0g = tb + w0l;

  const size_t row_base = ((size_t)n * C_ * H_ + (size_t)h) * W_;

  // y staging columns (clamped at image edges; clamped values only reach
  // disparity outputs the epilogue zeroes). Slot s holds col tb-12+s.
  int gy0 = tb - 12 + tid;
  gy0 = gy0 < 0 ? 0 : (gy0 > W_ - 1 ? W_ - 1 : gy0);
  int gy1 = tb - 12 + 256 + tid;
  gy1 = gy1 < 0 ? 0 : (gy1 > W_ - 1 ? W_ - 1 : gy1);
  const bool extra = tid < (YST - 256);  // 32 threads stage the y tail

  const float* py0 = y + row_base + gy0;
  const float* py1 = y + row_base + gy1;
  const float* xb = x + row_base + w0g;  // this thread's own 4 x cols
  float* op = out + (size_t)n * DISP_ * CH + (size_t)h * W_ + w0g;

  if (g == 0)
    body<0>(xb, py0, py1, extra, op, lds, tid, w0l, w0g);
  else if (g == 1)
    body<1>(xb, py0, py1, extra, op, lds, tid, w0l, w0g);
  else if (g == 2)
    body<2>(xb, py0, py1, extra, op, lds, tid, w0l, w0g);
  else
    body<3>(xb, py0, py1, extra, op, lds, tid, w0l, w0g);
}

extern "C" void kernel_launch(void* const* d_in, const int* in_sizes, int n_in,
                              void* d_out, int out_size, void* d_ws, size_t ws_size,
                              hipStream_t stream) {
  const float* x = (const float*)d_in[0];
  const float* y = (const float*)d_in[1];
  float* out = (float*)d_out;
  dim3 grid(N_ * H_ * 2);  // 256-col tile per block
  dim3 block(256);
  hipLaunchKernelGGL(rescost_kernel, grid, block, 0, stream, x, y, out);
}

// Round 21
// 68.694 us; speedup vs baseline: 1.4610x; 1.4610x over previous
//
#include <hip/hip_runtime.h>

namespace {
constexpr int N_ = 8, C_ = 32, H_ = 256, W_ = 512, DISP_ = 25;
constexpr int CH = H_ * W_;   // elements between channels / disparities
constexpr int TILE = 256;     // output columns per block
constexpr int NSS = C_ / 2;   // 16 supersteps, 2 channels packed per step
constexpr int YST = 288;      // staged y cols: [tb-12, tb+276)
constexpr int BUF = 296;      // u32 stride per buffer (288 + 8 pad; 16B-aligned)
}

typedef __attribute__((ext_vector_type(2))) _Float16 h2;
typedef __attribute__((ext_vector_type(4))) float f4;  // native vector for nt-store

__device__ __forceinline__ h2 u2h(unsigned u) { return __builtin_bit_cast(h2, u); }
__device__ __forceinline__ unsigned pk(float a, float b) {
  return __builtin_bit_cast(unsigned, __builtin_amdgcn_cvt_pkrtz(a, b));
}

// r21 = r20 (x-in-regs, y-only LDS) with __launch_bounds__(256,6) (was 8).
// r20 post-mortem: the (256,8) 64-reg cap spilled (WRITE 119 MB, +16.5 MB
// scratch; dur 100 us) -> LDS theory untested, not falsified. Cap ~102 regs
// at 6 waves/SIMD = r17's achieved residency, margin ~37 (rule satisfied).
// Clean A/B vs the 66 us baseline: LDS reads -25% (4->3 b128/superstep),
// LDS writes -40%, x served from registers via coalesced float4 loads
// (4 G-waves redundantly load same x; L1-served, L1 was at 33%).
// Predict 60-64 us if LDS is the tightest pipe; if flat ~66, declare
// roofline next round (mixed-traffic wall at ~58% of copy ceiling).
template <int G>
__device__ __forceinline__ void body(const float* xb, const float* py0,
                                     const float* py1, bool extra,
                                     float* __restrict__ op, unsigned* lds,
                                     int tid, int w0l, int w0g) {
  constexpr int I0 = (G == 0) ? 0 : (G == 1) ? 7 : (G == 2) ? 13 : 19;
  constexpr int NI = (G == 0) ? 7 : 6;
  constexpr int OFF = (G == 0) ? 4 : (G == 1) ? 0 : (G == 2) ? -8 : -12;

  const h2 one = {(_Float16)1.0f, (_Float16)1.0f};

  float acc[NI][4];
#pragma unroll
  for (int il = 0; il < NI; ++il)
#pragma unroll
    for (int cw = 0; cw < 4; ++cw) acc[il][cw] = 0.0f;

  float4 xl0, xl1;          // x cols w0..w0+3, channels 2s / 2s+1
  float b0, b1, c0, c1;     // y staging

#define YLOAD()                                                           \
  do {                                                                    \
    b0 = py0[0]; b1 = py0[CH];                                            \
    if (extra) { c0 = py1[0]; c1 = py1[CH]; }                             \
    py0 += 2 * CH; py1 += 2 * CH;                                         \
  } while (0)

#define XLOAD(s)                                                          \
  do {                                                                    \
    const float* xc = xb + (size_t)(2 * (s)) * CH;                        \
    xl0 = *reinterpret_cast<const float4*>(xc);                           \
    xl1 = *reinterpret_cast<const float4*>(xc + CH);                      \
  } while (0)

#define YWRITE(bsel)                                                      \
  do {                                                                    \
    unsigned* wp = lds + (bsel)*BUF;                                      \
    wp[tid] = pk(b0, b1);                                                 \
    if (extra) wp[256 + tid] = pk(c0, c1);                                \
  } while (0)

#define COMPUTE(bsel)                                                     \
  do {                                                                    \
    const unsigned* bp = lds + (bsel)*BUF;                                \
    const unsigned* yp = bp + w0l + (OFF + 12);                           \
    const uint4 q0 = *reinterpret_cast<const uint4*>(yp);                 \
    const uint4 q1 = *reinterpret_cast<const uint4*>(yp + 4);             \
    const uint4 q2 = *reinterpret_cast<const uint4*>(yp + 8);             \
    const unsigned yw[12] = {q0.x, q0.y, q0.z, q0.w, q1.x, q1.y, q1.z,    \
                             q1.w, q2.x, q2.y, q2.z, q2.w};               \
    _Pragma("unroll") for (int il = 0; il < NI; ++il) {                   \
      _Pragma("unroll") for (int cw = 0; cw < 4; ++cw) {                  \
        h2 d = u2h(xpk[cw]) - u2h(yw[cw + 12 - (I0 + il) - OFF]);         \
        h2 a = u2h(__builtin_bit_cast(unsigned, d) & 0x7FFF7FFFu);        \
        acc[il][cw] = __builtin_amdgcn_fdot2(a, one, acc[il][cw], false); \
      }                                                                   \
    }                                                                     \
  } while (0)

  // Prologue: superstep 0 (x to regs, y to LDS buffer 0).
  XLOAD(0);
  YLOAD();
  YWRITE(0);
  __syncthreads();

  int cb = 0;
#pragma unroll 1
  for (int s = 0; s < NSS; ++s) {
    // Consume xl into packed form, freeing xl for the next prefetch.
    const unsigned xpk[4] = {pk(xl0.x, xl1.x), pk(xl0.y, xl1.y),
                             pk(xl0.z, xl1.z), pk(xl0.w, xl1.w)};
    const bool more = (s + 1 < NSS);
    if (more) { XLOAD(s + 1); YLOAD(); }  // full compute phase of slack
    COMPUTE(cb);                          // 3 ds_read_b128 + fdot2 chain
    if (more) YWRITE(cb ^ 1);             // waits on y loads only
    __syncthreads();                      // writes visible; buffers ordered
    cb ^= 1;
  }

#undef YLOAD
#undef XLOAD
#undef YWRITE
#undef COMPUTE

  // Epilogue: zero out-of-overlap (w,i) pairs; NON-TEMPORAL stores (output
  // is write-once/never-read -> evict-first keeps it out of L2/L3).
#pragma unroll
  for (int il = 0; il < NI; ++il) {
    const int i = I0 + il;
    const int j0 = w0g - i + 12;  // y column used by cw=0
    f4 v;
    v.x = ((unsigned)(j0 + 0) < (unsigned)W_) ? acc[il][0] : 0.0f;
    v.y = ((unsigned)(j0 + 1) < (unsigned)W_) ? acc[il][1] : 0.0f;
    v.z = ((unsigned)(j0 + 2) < (unsigned)W_) ? acc[il][2] : 0.0f;
    v.w = ((unsigned)(j0 + 3) < (unsigned)W_) ? acc[il][3] : 0.0f;
    __builtin_nontemporal_store(v, reinterpret_cast<f4*>(op + (size_t)i * CH));
  }
}

__global__ __launch_bounds__(256, 6) void rescost_kernel(
    const float* __restrict__ x, const float* __restrict__ y,
    float* __restrict__ out) {
  __shared__ __align__(16) unsigned lds[2 * BUF];  // 2368 B, y only

  const int tid = threadIdx.x;
  const int tl = tid & 63;   // column group within tile: w0l = 4*tl
  const int g = tid >> 6;    // disparity group (wave-uniform)
  const int bid = blockIdx.x;
  const int tile = bid & 1;  // which 256-col half of the row
  const int r = bid >> 1;    // row in [0, N*H)
  const int n = r >> 8;      // H = 256
  const int h = r & (H_ - 1);
  const int tb = tile * TILE;
  const int w0l = tl << 2;
  const int w0g = tb + w0l;

  const size_t row_base = ((size_t)n * C_ * H_ + (size_t)h) * W_;

  // y staging columns (clamped at image edges; clamped values only reach
  // disparity outputs the epilogue zeroes). Slot s holds col tb-12+s.
  int gy0 = tb - 12 + tid;
  gy0 = gy0 < 0 ? 0 : (gy0 > W_ - 1 ? W_ - 1 : gy0);
  int gy1 = tb - 12 + 256 + tid;
  gy1 = gy1 < 0 ? 0 : (gy1 > W_ - 1 ? W_ - 1 : gy1);
  const bool extra = tid < (YST - 256);  // 32 threads stage the y tail

  const float* py0 = y + row_base + gy0;
  const float* py1 = y + row_base + gy1;
  const float* xb = x + row_base + w0g;  // this thread's own 4 x cols
  float* op = out + (size_t)n * DISP_ * CH + (size_t)h * W_ + w0g;

  if (g == 0)
    body<0>(xb, py0, py1, extra, op, lds, tid, w0l, w0g);
  else if (g == 1)
    body<1>(xb, py0, py1, extra, op, lds, tid, w0l, w0g);
  else if (g == 2)
    body<2>(xb, py0, py1, extra, op, lds, tid, w0l, w0g);
  else
    body<3>(xb, py0, py1, extra, op, lds, tid, w0l, w0g);
}

extern "C" void kernel_launch(void* const* d_in, const int* in_sizes, int n_in,
                              void* d_out, int out_size, void* d_ws, size_t ws_size,
                              hipStream_t stream) {
  const float* x = (const float*)d_in[0];
  const float* y = (const float*)d_in[1];
  float* out = (float*)d_out;
  dim3 grid(N_ * H_ * 2);  // 256-col tile per block
  dim3 block(256);
  hipLaunchKernelGGL(rescost_kernel, grid, block, 0, stream, x, y, out);
}

// Round 22
// 65.077 us; speedup vs baseline: 1.5422x; 1.0556x over previous
//
#include <hip/hip_runtime.h>

namespace {
constexpr int N_ = 8, C_ = 32, H_ = 256, W_ = 512, DISP_ = 25;
constexpr int CH = H_ * W_;   // elements between channels / disparities
constexpr int TILE = 256;     // output columns per block
constexpr int NSS = C_ / 2;   // 16 supersteps, 2 channels packed per step
constexpr int YST = 288;      // staged y cols: [tb-12, tb+276)
constexpr int YOFF = 256;     // y region start (u32 units) inside a buffer
constexpr int BUF = 560;      // u32 stride per buffer
}

typedef __attribute__((ext_vector_type(2))) _Float16 h2;
typedef __attribute__((ext_vector_type(4))) float f4;  // native vector for nt-store

__device__ __forceinline__ h2 u2h(unsigned u) { return __builtin_bit_cast(h2, u); }
__device__ __forceinline__ unsigned h2u(h2 v) { return __builtin_bit_cast(unsigned, v); }

// FINAL (r22) = r18 verbatim, the session optimum: 66.2 us.
// Packed-f16 channel pairs (cvt_pkrtz at staging), f32 accumulation via
// v_dot2_f32_f16 (absmax 0.5 << 1.31 threshold), LDS double-buffered y
// windows, x+y staged per 2-channel superstep, NON-TEMPORAL output stores
// (write-once data bypasses L2/L3 write-allocate -- the single biggest win,
// 81 -> 67 us), launch_bounds(256,8).
// Roofline evidence (21 rounds): compulsory traffic 139 MB fetch (L3
// capacity: 256 MB inputs vs 256 MB L3) + 102 MB nt-write = 241 MB at
// 3.65 TB/s sustained mixed BW = 58% of pure-copy ceiling; VALU ~54%,
// LDS ~50%, L1 ~33% co-running. Four post-r17 single-variable levers
// (occupancy, barrier count, halo, LDS load) each moved <= +/-2.5 us.
template <int G>
__device__ __forceinline__ void body(const float* px, const float* py0,
                                     const float* py1, bool extra,
                                     float* __restrict__ op, unsigned* lds,
                                     int tid, int w0l, int w0g) {
  constexpr int I0 = (G == 0) ? 0 : (G == 1) ? 7 : (G == 2) ? 13 : 19;
  constexpr int NI = (G == 0) ? 7 : 6;
  constexpr int OFF = (G == 0) ? 4 : (G == 1) ? 0 : (G == 2) ? -8 : -12;

  const h2 one = {(_Float16)1.0f, (_Float16)1.0f};

  float acc[NI][4];
#pragma unroll
  for (int il = 0; il < NI; ++il)
#pragma unroll
    for (int cw = 0; cw < 4; ++cw) acc[il][cw] = 0.0f;

  float a0, a1, b0, b1, c0, c1;

#define SLOAD()                                                           \
  do {                                                                    \
    a0 = px[0]; a1 = px[CH];                                              \
    b0 = py0[0]; b1 = py0[CH];                                            \
    if (extra) { c0 = py1[0]; c1 = py1[CH]; }                             \
    px += 2 * CH; py0 += 2 * CH; py1 += 2 * CH;                           \
  } while (0)

#define SWRITE(bsel)                                                      \
  do {                                                                    \
    unsigned* wp = lds + (bsel)*BUF;                                      \
    h2 pa = __builtin_bit_cast(h2, __builtin_amdgcn_cvt_pkrtz(a0, a1));   \
    h2 pb = __builtin_bit_cast(h2, __builtin_amdgcn_cvt_pkrtz(b0, b1));   \
    wp[tid] = h2u(pa);                                                    \
    wp[YOFF + tid] = h2u(pb);                                             \
    if (extra) {                                                          \
      h2 pc = __builtin_bit_cast(h2, __builtin_amdgcn_cvt_pkrtz(c0, c1)); \
      wp[YOFF + 256 + tid] = h2u(pc);                                     \
    }                                                                     \
  } while (0)

#define COMPUTE(bsel)                                                     \
  do {                                                                    \
    const unsigned* bp = lds + (bsel)*BUF;                                \
    const uint4 xq = *reinterpret_cast<const uint4*>(bp + w0l);           \
    const uint4 q0 = *reinterpret_cast<const uint4*>(bp + YOFF + w0l +    \
                                                     (OFF + 12));         \
    const uint4 q1 = *reinterpret_cast<const uint4*>(bp + YOFF + w0l +    \
                                                     (OFF + 12) + 4);    \
    const uint4 q2 = *reinterpret_cast<const uint4*>(bp + YOFF + w0l +    \
                                                     (OFF + 12) + 8);    \
    const unsigned xs[4] = {xq.x, xq.y, xq.z, xq.w};                      \
    const unsigned yw[12] = {q0.x, q0.y, q0.z, q0.w, q1.x, q1.y, q1.z,    \
                             q1.w, q2.x, q2.y, q2.z, q2.w};               \
    _Pragma("unroll") for (int il = 0; il < NI; ++il) {                   \
      _Pragma("unroll") for (int cw = 0; cw < 4; ++cw) {                  \
        h2 d = u2h(xs[cw]) - u2h(yw[cw + 12 - (I0 + il) - OFF]);          \
        h2 a = u2h(h2u(d) & 0x7FFF7FFFu);                                 \
        acc[il][cw] = __builtin_amdgcn_fdot2(a, one, acc[il][cw], false); \
      }                                                                   \
    }                                                                     \
  } while (0)

  // Prologue: stage superstep 0 into buffer 0.
  SLOAD();
  SWRITE(0);
  __syncthreads();

  int cb = 0;
#pragma unroll 1
  for (int s = 0; s < NSS; ++s) {
    const bool more = (s + 1 < NSS);
    if (more) SLOAD();   // issue next superstep's global loads early
    COMPUTE(cb);         // compute hides the load latency
    if (more) SWRITE(cb ^ 1);
    __syncthreads();     // writes visible; buffer reuse ordered
    cb ^= 1;
  }

#undef SLOAD
#undef SWRITE
#undef COMPUTE

  // Epilogue: zero out-of-overlap (w,i) pairs; NON-TEMPORAL stores (output
  // is write-once/never-read -> evict-first keeps it out of L2/L3).
#pragma unroll
  for (int il = 0; il < NI; ++il) {
    const int i = I0 + il;
    const int j0 = w0g - i + 12;  // y column used by cw=0
    f4 v;
    v.x = ((unsigned)(j0 + 0) < (unsigned)W_) ? acc[il][0] : 0.0f;
    v.y = ((unsigned)(j0 + 1) < (unsigned)W_) ? acc[il][1] : 0.0f;
    v.z = ((unsigned)(j0 + 2) < (unsigned)W_) ? acc[il][2] : 0.0f;
    v.w = ((unsigned)(j0 + 3) < (unsigned)W_) ? acc[il][3] : 0.0f;
    __builtin_nontemporal_store(v, reinterpret_cast<f4*>(op + (size_t)i * CH));
  }
}

__global__ __launch_bounds__(256, 8) void rescost_kernel(
    const float* __restrict__ x, const float* __restrict__ y,
    float* __restrict__ out) {
  __shared__ __align__(16) unsigned lds[2 * BUF];  // 4480 B

  const int tid = threadIdx.x;
  const int tl = tid & 63;   // column group within tile
  const int g = tid >> 6;    // disparity group (wave-uniform)
  const int bid = blockIdx.x;
  const int tile = bid & 1;  // which 256-col half of the row
  const int r = bid >> 1;    // row in [0, N*H)
  const int n = r >> 8;      // H = 256
  const int h = r & (H_ - 1);
  const int tb = tile * TILE;
  const int w0l = tl << 2;
  const int w0g = tb + w0l;

  const size_t row_base = ((size_t)n * C_ * H_ + (size_t)h) * W_;

  // Staging columns (clamped at image edges; clamped values only reach
  // disparity outputs the epilogue zeroes).
  const int gx = tb + tid;
  int gy0 = tb - 12 + tid;
  gy0 = gy0 < 0 ? 0 : (gy0 > W_ - 1 ? W_ - 1 : gy0);
  int gy1 = tb - 12 + 256 + tid;
  gy1 = gy1 < 0 ? 0 : (gy1 > W_ - 1 ? W_ - 1 : gy1);
  const bool extra = tid < (YST - 256);  // 32 threads stage the y tail

  const float* px = x + row_base + gx;
  const float* py0 = y + row_base + gy0;
  const float* py1 = y + row_base + gy1;
  float* op = out + (size_t)n * DISP_ * CH + (size_t)h * W_ + w0g;

  if (g == 0)
    body<0>(px, py0, py1, extra, op, lds, tid, w0l, w0g);
  else if (g == 1)
    body<1>(px, py0, py1, extra, op, lds, tid, w0l, w0g);
  else if (g == 2)
    body<2>(px, py0, py1, extra, op, lds, tid, w0l, w0g);
  else
    body<3>(px, py0, py1, extra, op, lds, tid, w0l, w0g);
}

extern "C" void kernel_launch(void* const* d_in, const int* in_sizes, int n_in,
                              void* d_out, int out_size, void* d_ws, size_t ws_size,
                              hipStream_t stream) {
  const float* x = (const float*)d_in[0];
  const float* y = (const float*)d_in[1];
  float* out = (float*)d_out;
  dim3 grid(N_ * H_ * 2);  // 256-col tile per block
  dim3 block(256);
  hipLaunchKernelGGL(rescost_kernel, grid, block, 0, stream, x, y, out);
}